// Round 6
// baseline (396.486 us; speedup 1.0000x reference)
//
#include <hip/hip_runtime.h>

// ---------------------------------------------------------------------------
// Barrier-free wave-autonomous design, TRANSPOSED MFMA epilogue.
// Round 6: minimal-diff experiment. Rounds 3-5 all bundled body changes and
// all were scratch-poisoned (WRITE_SIZE 100/381/203 MB vs round-0's 25 MB);
// the trigger could not be isolated from counters. This round reverts to the
// EXACT round-0 body (only clean measurement: 172us kF, zero scratch) and
// changes ONE variable: launch geometry. 2 waves/block (128 thr), LDS
// 23040 B/block, __launch_bounds__(128,4) -> 7 blocks/CU x 2 waves =
// 14 waves/CU vs round-0's 12. Occupancy lever on a latency-bound kernel,
// and a scratch bisection: if scratch appears here, the trigger is launch
// geometry/compiler, not the round-1+ body edits.
// ---------------------------------------------------------------------------

#define ASTR 72   // act row stride in shorts

typedef short v8s __attribute__((ext_vector_type(8)));
typedef float v4f __attribute__((ext_vector_type(4)));

#define MFMA __builtin_amdgcn_mfma_f32_16x16x32_bf16

// ws layout (offsets in shorts)
#define OFF_PW1 0                        // 64 x 32 (K=16 zero-padded to 32)
#define OFF_PW2 2048                     // 64 x 64
#define OFF_LW1(L) (6144 + (L) * 6144)   // 64 x 64
#define OFF_LW2(L) (OFF_LW1(L) + 4096)   // 32 x 64
#define OFF_OW1 24576                    // 64 x 64
#define OFF_OW2 28672                    // 128 x 64

__device__ __forceinline__ short bfb(float v) {
  __bf16 b = (__bf16)v;
  return __builtin_bit_cast(short, b);
}

// ---- kT: transpose weights into bf16 B-fragment layout in ws ----
__global__ void kT(const float* __restrict__ pw1, const float* __restrict__ pw2,
                   const float* __restrict__ w1a, const float* __restrict__ w2a,
                   const float* __restrict__ w1b, const float* __restrict__ w2b,
                   const float* __restrict__ w1c, const float* __restrict__ w2c,
                   const float* __restrict__ ow1, const float* __restrict__ ow2,
                   short* __restrict__ ws) {
  const float* W; int K, F, Kpad, off;
  switch (blockIdx.x) {
    case 0: W = pw1; K = 16; F = 64;  Kpad = 32; off = OFF_PW1; break;
    case 1: W = pw2; K = 64; F = 64;  Kpad = 64; off = OFF_PW2; break;
    case 2: W = w1a; K = 64; F = 64;  Kpad = 64; off = OFF_LW1(0); break;
    case 3: W = w2a; K = 64; F = 32;  Kpad = 64; off = OFF_LW2(0); break;
    case 4: W = w1b; K = 64; F = 64;  Kpad = 64; off = OFF_LW1(1); break;
    case 5: W = w2b; K = 64; F = 32;  Kpad = 64; off = OFF_LW2(1); break;
    case 6: W = w1c; K = 64; F = 64;  Kpad = 64; off = OFF_LW1(2); break;
    case 7: W = w2c; K = 64; F = 32;  Kpad = 64; off = OFF_LW2(2); break;
    case 8: W = ow1; K = 64; F = 64;  Kpad = 64; off = OFF_OW1; break;
    default: W = ow2; K = 64; F = 128; Kpad = 64; off = OFF_OW2; break;
  }
  const int total = F * (Kpad >> 3);
  for (int i = threadIdx.x; i < total; i += blockDim.x) {
    const int f = i % F;
    const int kq = i / F;
    v8s h;
#pragma unroll
    for (int j = 0; j < 8; ++j) {
      const int k = kq * 8 + j;
      h[j] = bfb((k < K) ? W[k * F + f] : 0.f);
    }
    *(v8s*)(ws + off + f * Kpad + kq * 8) = h;
  }
}

// Transposed matmul over one 16-node tile: acc[t] covers features t*16..+15.
template <int NT, int KS>
__device__ __forceinline__ void mmT(const short* A, int tb, const v8s* Wf,
                                    const v4f* bias4, int col, int quad,
                                    v4f* acc) {
#pragma unroll
  for (int t = 0; t < NT; ++t) acc[t] = bias4[t];
#pragma unroll
  for (int ks = 0; ks < KS; ++ks) {
    const v8s b = *(const v8s*)(A + (tb + col) * ASTR + ks * 32 + quad * 8);
#pragma unroll
    for (int t = 0; t < NT; ++t)
      acc[t] = MFMA(Wf[t * KS + ks], b, acc[t], 0, 0, 0);
  }
}

// LayerNorm(64)+ReLU, features in-lane; short4 (b64) writes.
__device__ __forceinline__ void lnT_write(short* Aw, int tb, int col, int quad,
                                          v4f* acc, const v4f* g4,
                                          const v4f* be4) {
  float mu = 0.f, sq = 0.f;
#pragma unroll
  for (int t = 0; t < 4; ++t)
#pragma unroll
    for (int r = 0; r < 4; ++r) {
      mu += acc[t][r];
      sq = fmaf(acc[t][r], acc[t][r], sq);
    }
  mu += __shfl_xor(mu, 16); mu += __shfl_xor(mu, 32);
  sq += __shfl_xor(sq, 16); sq += __shfl_xor(sq, 32);
  mu *= (1.0f / 64.0f);
  const float var = sq * (1.0f / 64.0f) - mu * mu;
  const float rs = rsqrtf(var + 1e-5f);
#pragma unroll
  for (int t = 0; t < 4; ++t) {
    short4 s;
#pragma unroll
    for (int r = 0; r < 4; ++r) {
      float v = fmaf((acc[t][r] - mu) * rs, g4[t][r], be4[t][r]);
      ((short*)&s)[r] = bfb(fmaxf(v, 0.f));
    }
    *(short4*)(Aw + (tb + col) * ASTR + t * 16 + quad * 4) = s;
  }
}

template <int NT>
__device__ __forceinline__ void plainT_write(short* Aw, int tb, int col,
                                             int quad, v4f* acc) {
#pragma unroll
  for (int t = 0; t < NT; ++t) {
    short4 s;
#pragma unroll
    for (int r = 0; r < 4; ++r) ((short*)&s)[r] = bfb(acc[t][r]);
    *(short4*)(Aw + (tb + col) * ASTR + t * 16 + quad * 4) = s;
  }
}

// ---- kF: the whole network, one wave = 4 clusters, zero barriers ----
// Round-0 body; only launch geometry changed (2 waves/block).
__global__ void __launch_bounds__(128, 4)
kF(const float* __restrict__ x, const int* __restrict__ batch,
   const short* __restrict__ wsW,
   const float* __restrict__ pb1, const float* __restrict__ pg,
   const float* __restrict__ pbe, const float* __restrict__ pb2,
   const float* __restrict__ b1a, const float* __restrict__ ga,
   const float* __restrict__ bea, const float* __restrict__ b2a,
   const float* __restrict__ b1b, const float* __restrict__ gb,
   const float* __restrict__ beb, const float* __restrict__ b2b,
   const float* __restrict__ b1c, const float* __restrict__ gc_,
   const float* __restrict__ bec, const float* __restrict__ b2c,
   const float* __restrict__ ob1, const float* __restrict__ og,
   const float* __restrict__ obe, const float* __restrict__ ob2,
   float* __restrict__ out, int C) {
  __shared__ __align__(16) short act[2 * 80 * ASTR];   // 23040 B
  const int tid = threadIdx.x;
  const int lane = tid & 63;
  const int wave = tid >> 6;
  const int col = lane & 15;
  const int quad = lane >> 4;
  const int cbase = blockIdx.x * 8 + wave * 4;
  if (cbase >= C) return;
  const int nc = min(4, C - cbase);
  const int nrows = nc * 20;
  const int ntiles = (nrows + 15) >> 4;
  short* A = act + wave * 80 * ASTR;

  // ---- load x -> bf16 cols 0..15, zero cols 16..31 ----
  {
    const float4* x4 = (const float4*)x;
    const long nb = (long)cbase * 20;
    const short4 z = {0, 0, 0, 0};
    for (int i = lane; i < nrows * 4; i += 64) {
      const int row = i >> 2, e = i & 3;
      float4 v = x4[(nb + row) * 4 + e];
      short4 s = {bfb(v.x), bfb(v.y), bfb(v.z), bfb(v.w)};
      *(short4*)(A + row * ASTR + e * 4) = s;
      *(short4*)(A + row * ASTR + 16 + e * 4) = z;
    }
    if (nrows < ntiles * 16) {
      for (int i = lane; i < (ntiles * 16 - nrows) * 18; i += 64) {
        const int row = nrows + i / 18, e = i % 18;
        *(short4*)(A + row * ASTR + e * 4) = z;
      }
    }
  }

  // ---- pre-MLP stage 1: 16(pad32) -> 64, LN, ReLU ----
  {
    v8s Wf[4]; v4f b4[4], g4[4], be4[4];
#pragma unroll
    for (int t = 0; t < 4; ++t) {
      Wf[t] = *(const v8s*)(wsW + OFF_PW1 + (t * 16 + col) * 32 + quad * 8);
      b4[t]  = *(const v4f*)(pb1 + t * 16 + quad * 4);
      g4[t]  = *(const v4f*)(pg  + t * 16 + quad * 4);
      be4[t] = *(const v4f*)(pbe + t * 16 + quad * 4);
    }
    for (int T = 0; T < ntiles; ++T) {
      v4f acc[4];
      mmT<4, 1>(A, T * 16, Wf, b4, col, quad, acc);
      lnT_write(A, T * 16, col, quad, acc, g4, be4);
    }
  }

  // ---- pre-MLP stage 2: 64 -> 64 (no LN) ----
  {
    v8s Wf[8]; v4f b4[4];
#pragma unroll
    for (int t = 0; t < 4; ++t) {
#pragma unroll
      for (int ks = 0; ks < 2; ++ks)
        Wf[t * 2 + ks] = *(const v8s*)(wsW + OFF_PW2 + (t * 16 + col) * 64 + ks * 32 + quad * 8);
      b4[t] = *(const v4f*)(pb2 + t * 16 + quad * 4);
    }
    for (int T = 0; T < ntiles; ++T) {
      v4f acc[4];
      mmT<4, 2>(A, T * 16, Wf, b4, col, quad, acc);
      plainT_write<4>(A, T * 16, col, quad, acc);
    }
  }

  // ---- 3 subgraph layers ----
  const float* B1p[3] = {b1a, b1b, b1c};
  const float* Gp[3]  = {ga, gb, gc_};
  const float* BEp[3] = {bea, beb, bec};
  const float* B2p[3] = {b2a, b2b, b2c};

  for (int L = 0; L < 3; ++L) {
    v8s W1f[8], W2f[4];
    v4f b14[4], g4[4], be4[4], b24[2];
    const short* w1 = wsW + OFF_LW1(L);
    const short* w2 = wsW + OFF_LW2(L);
#pragma unroll
    for (int t = 0; t < 4; ++t) {
#pragma unroll
      for (int ks = 0; ks < 2; ++ks)
        W1f[t * 2 + ks] = *(const v8s*)(w1 + (t * 16 + col) * 64 + ks * 32 + quad * 8);
      b14[t] = *(const v4f*)(B1p[L] + t * 16 + quad * 4);
      g4[t]  = *(const v4f*)(Gp[L]  + t * 16 + quad * 4);
      be4[t] = *(const v4f*)(BEp[L] + t * 16 + quad * 4);
    }
#pragma unroll
    for (int t = 0; t < 2; ++t) {
#pragma unroll
      for (int ks = 0; ks < 2; ++ks)
        W2f[t * 2 + ks] = *(const v8s*)(w2 + (t * 16 + col) * 64 + ks * 32 + quad * 8);
      b24[t] = *(const v4f*)(B2p[L] + t * 16 + quad * 4);
    }
    for (int T = 0; T < ntiles; ++T) {
      v4f acc[4];
      mmT<4, 2>(A, T * 16, W1f, b14, col, quad, acc);
      lnT_write(A, T * 16, col, quad, acc, g4, be4);
      v4f h[2];
      mmT<2, 2>(A, T * 16, W2f, b24, col, quad, h);
      plainT_write<2>(A, T * 16, col, quad, h);
    }
    // ---- intra-wave pooling: 4 clusters x 16 uint-cols ----
    {
      const int cl = quad, jp = col;
      if (cl < nc) {
        const uint* AU = (const uint*)A;
        float m0 = -3.4e38f, m1 = -3.4e38f;
#pragma unroll
        for (int r = 0; r < 20; ++r) {
          const uint v = AU[(cl * 20 + r) * (ASTR / 2) + jp];
          m0 = fmaxf(m0, __builtin_bit_cast(float, v << 16));
          m1 = fmaxf(m1, __builtin_bit_cast(float, v & 0xFFFF0000u));
        }
        const uint pv = (uint)(unsigned short)bfb(m0) |
                        ((uint)(unsigned short)bfb(m1) << 16);
        uint* AW = (uint*)A;
        if (L < 2) {
#pragma unroll
          for (int r = 0; r < 20; ++r)
            AW[(cl * 20 + r) * (ASTR / 2) + 16 + jp] = pv;
        } else {
          // segmax(concat[h,pooled]) == [pooled,pooled] -> rows 0..3 = pooled
          AW[cl * (ASTR / 2) + jp] = pv;
          AW[cl * (ASTR / 2) + 16 + jp] = pv;
        }
      }
    }
  }

  // ---- fused output MLP on rows 0..15 (rows 0..nc-1 valid) ----
  {
    v8s Wf[8]; v4f b4[4], g4[4], be4[4];
#pragma unroll
    for (int t = 0; t < 4; ++t) {
#pragma unroll
      for (int ks = 0; ks < 2; ++ks)
        Wf[t * 2 + ks] = *(const v8s*)(wsW + OFF_OW1 + (t * 16 + col) * 64 + ks * 32 + quad * 8);
      b4[t]  = *(const v4f*)(ob1 + t * 16 + quad * 4);
      g4[t]  = *(const v4f*)(og  + t * 16 + quad * 4);
      be4[t] = *(const v4f*)(obe + t * 16 + quad * 4);
    }
    v4f acc[4];
    mmT<4, 2>(A, 0, Wf, b4, col, quad, acc);
    lnT_write(A, 0, col, quad, acc, g4, be4);
  }
  {
    v4f acc[8];
    const v8s bb0 = *(const v8s*)(A + col * ASTR + quad * 8);
    const v8s bb1 = *(const v8s*)(A + col * ASTR + 32 + quad * 8);
#pragma unroll
    for (int half = 0; half < 2; ++half) {
      v8s Wf[8];
#pragma unroll
      for (int t = 0; t < 4; ++t)
#pragma unroll
        for (int ks = 0; ks < 2; ++ks)
          Wf[t * 2 + ks] = *(const v8s*)(wsW + OFF_OW2 +
                             ((half * 4 + t) * 16 + col) * 64 + ks * 32 + quad * 8);
#pragma unroll
      for (int t = 0; t < 4; ++t) {
        v4f a = *(const v4f*)(ob2 + (half * 4 + t) * 16 + quad * 4);
        a = MFMA(Wf[t * 2], bb0, a, 0, 0, 0);
        a = MFMA(Wf[t * 2 + 1], bb1, a, 0, 0, 0);
        acc[half * 4 + t] = a;
      }
    }
    // L2 norm over 128 feats (32 in-lane + cross-quad)
    float sq = 0.f;
#pragma unroll
    for (int t = 0; t < 8; ++t)
#pragma unroll
      for (int r = 0; r < 4; ++r) sq = fmaf(acc[t][r], acc[t][r], sq);
    sq += __shfl_xor(sq, 16); sq += __shfl_xor(sq, 32);
    const float inv = 1.0f / fmaxf(sqrtf(sq), 1e-12f);
    if (col < nc) {
      const long gcl = cbase + col;
#pragma unroll
      for (int t = 0; t < 8; ++t) {
        float4 v = {acc[t][0] * inv, acc[t][1] * inv,
                    acc[t][2] * inv, acc[t][3] * inv};
        *(float4*)(out + gcl * 128 + t * 16 + quad * 4) = v;
      }
      if (quad == 0) out[(long)C * 128 + gcl] = (float)batch[gcl * 20];
    }
  }
}

extern "C" void kernel_launch(void* const* d_in, const int* in_sizes, int n_in,
                              void* d_out, int out_size, void* d_ws, size_t ws_size,
                              hipStream_t stream) {
  const float* x     = (const float*)d_in[0];
  const int*   batch = (const int*)d_in[2];
  const float* pw1 = (const float*)d_in[3];
  const float* pb1 = (const float*)d_in[4];
  const float* pg  = (const float*)d_in[5];
  const float* pbe = (const float*)d_in[6];
  const float* pw2 = (const float*)d_in[7];
  const float* pb2 = (const float*)d_in[8];
  const float* w1a = (const float*)d_in[9];
  const float* b1a = (const float*)d_in[10];
  const float* ga  = (const float*)d_in[11];
  const float* bea = (const float*)d_in[12];
  const float* w2a = (const float*)d_in[13];
  const float* b2a = (const float*)d_in[14];
  const float* w1b = (const float*)d_in[15];
  const float* b1b = (const float*)d_in[16];
  const float* gb  = (const float*)d_in[17];
  const float* beb = (const float*)d_in[18];
  const float* w2b = (const float*)d_in[19];
  const float* b2b = (const float*)d_in[20];
  const float* w1c = (const float*)d_in[21];
  const float* b1c = (const float*)d_in[22];
  const float* gc  = (const float*)d_in[23];
  const float* bec = (const float*)d_in[24];
  const float* w2c = (const float*)d_in[25];
  const float* b2c = (const float*)d_in[26];
  const float* ow1 = (const float*)d_in[27];
  const float* ob1 = (const float*)d_in[28];
  const float* og  = (const float*)d_in[29];
  const float* obe = (const float*)d_in[30];
  const float* ow2 = (const float*)d_in[31];
  const float* ob2 = (const float*)d_in[32];

  const int N = in_sizes[0] / 16;
  const int C = N / 20;
  short* ws16 = (short*)d_ws;
  float* out = (float*)d_out;

  hipLaunchKernelGGL(kT, dim3(10), dim3(256), 0, stream,
                     pw1, pw2, w1a, w2a, w1b, w2b, w1c, w2c, ow1, ow2, ws16);

  const int blocks = (C + 7) / 8;   // 8 clusters per block (2 waves x 4)
  hipLaunchKernelGGL(kF, dim3(blocks), dim3(128), 0, stream,
                     x, batch, (const short*)ws16,
                     pb1, pg, pbe, pb2,
                     b1a, ga, bea, b2a,
                     b1b, gb, beb, b2b,
                     b1c, gc, bec, b2c,
                     ob1, og, obe, ob2,
                     out, C);
}

// Round 7
// 309.063 us; speedup vs baseline: 1.2829x; 1.2829x over previous
//
#include <hip/hip_runtime.h>

// ---------------------------------------------------------------------------
// Barrier-free wave-autonomous design, TRANSPOSED MFMA epilogue.
// Round 7: round 6 isolated the scratch trigger — __launch_bounds__(128,4)
// capped VGPR to 64 (< body's natural 76) and forced spills (WRITE_SIZE
// 25->120 MB). Same mechanism explains rounds 3-5 (caps 170/84 vs unrolled
// bodies' live state). This round: round-6 source with ONE token changed,
// __launch_bounds__(128,2) -> VGPR cap >=256 under either arg
// interpretation, no forced spill. Geometry lever kept: 2-wave blocks,
// 23040 B LDS -> 7 blocks/CU = 14 waves/CU vs round-0's 12 on a
// latency-bound kernel. R6 already validated this body+geometry for
// correctness (passed, same absmax).
// ---------------------------------------------------------------------------

#define ASTR 72   // act row stride in shorts

typedef short v8s __attribute__((ext_vector_type(8)));
typedef float v4f __attribute__((ext_vector_type(4)));

#define MFMA __builtin_amdgcn_mfma_f32_16x16x32_bf16

// ws layout (offsets in shorts)
#define OFF_PW1 0                        // 64 x 32 (K=16 zero-padded to 32)
#define OFF_PW2 2048                     // 64 x 64
#define OFF_LW1(L) (6144 + (L) * 6144)   // 64 x 64
#define OFF_LW2(L) (OFF_LW1(L) + 4096)   // 32 x 64
#define OFF_OW1 24576                    // 64 x 64
#define OFF_OW2 28672                    // 128 x 64

__device__ __forceinline__ short bfb(float v) {
  __bf16 b = (__bf16)v;
  return __builtin_bit_cast(short, b);
}

// ---- kT: transpose weights into bf16 B-fragment layout in ws ----
__global__ void kT(const float* __restrict__ pw1, const float* __restrict__ pw2,
                   const float* __restrict__ w1a, const float* __restrict__ w2a,
                   const float* __restrict__ w1b, const float* __restrict__ w2b,
                   const float* __restrict__ w1c, const float* __restrict__ w2c,
                   const float* __restrict__ ow1, const float* __restrict__ ow2,
                   short* __restrict__ ws) {
  const float* W; int K, F, Kpad, off;
  switch (blockIdx.x) {
    case 0: W = pw1; K = 16; F = 64;  Kpad = 32; off = OFF_PW1; break;
    case 1: W = pw2; K = 64; F = 64;  Kpad = 64; off = OFF_PW2; break;
    case 2: W = w1a; K = 64; F = 64;  Kpad = 64; off = OFF_LW1(0); break;
    case 3: W = w2a; K = 64; F = 32;  Kpad = 64; off = OFF_LW2(0); break;
    case 4: W = w1b; K = 64; F = 64;  Kpad = 64; off = OFF_LW1(1); break;
    case 5: W = w2b; K = 64; F = 32;  Kpad = 64; off = OFF_LW2(1); break;
    case 6: W = w1c; K = 64; F = 64;  Kpad = 64; off = OFF_LW1(2); break;
    case 7: W = w2c; K = 64; F = 32;  Kpad = 64; off = OFF_LW2(2); break;
    case 8: W = ow1; K = 64; F = 64;  Kpad = 64; off = OFF_OW1; break;
    default: W = ow2; K = 64; F = 128; Kpad = 64; off = OFF_OW2; break;
  }
  const int total = F * (Kpad >> 3);
  for (int i = threadIdx.x; i < total; i += blockDim.x) {
    const int f = i % F;
    const int kq = i / F;
    v8s h;
#pragma unroll
    for (int j = 0; j < 8; ++j) {
      const int k = kq * 8 + j;
      h[j] = bfb((k < K) ? W[k * F + f] : 0.f);
    }
    *(v8s*)(ws + off + f * Kpad + kq * 8) = h;
  }
}

// Transposed matmul over one 16-node tile: acc[t] covers features t*16..+15.
template <int NT, int KS>
__device__ __forceinline__ void mmT(const short* A, int tb, const v8s* Wf,
                                    const v4f* bias4, int col, int quad,
                                    v4f* acc) {
#pragma unroll
  for (int t = 0; t < NT; ++t) acc[t] = bias4[t];
#pragma unroll
  for (int ks = 0; ks < KS; ++ks) {
    const v8s b = *(const v8s*)(A + (tb + col) * ASTR + ks * 32 + quad * 8);
#pragma unroll
    for (int t = 0; t < NT; ++t)
      acc[t] = MFMA(Wf[t * KS + ks], b, acc[t], 0, 0, 0);
  }
}

// LayerNorm(64)+ReLU, features in-lane; short4 (b64) writes.
__device__ __forceinline__ void lnT_write(short* Aw, int tb, int col, int quad,
                                          v4f* acc, const v4f* g4,
                                          const v4f* be4) {
  float mu = 0.f, sq = 0.f;
#pragma unroll
  for (int t = 0; t < 4; ++t)
#pragma unroll
    for (int r = 0; r < 4; ++r) {
      mu += acc[t][r];
      sq = fmaf(acc[t][r], acc[t][r], sq);
    }
  mu += __shfl_xor(mu, 16); mu += __shfl_xor(mu, 32);
  sq += __shfl_xor(sq, 16); sq += __shfl_xor(sq, 32);
  mu *= (1.0f / 64.0f);
  const float var = sq * (1.0f / 64.0f) - mu * mu;
  const float rs = rsqrtf(var + 1e-5f);
#pragma unroll
  for (int t = 0; t < 4; ++t) {
    short4 s;
#pragma unroll
    for (int r = 0; r < 4; ++r) {
      float v = fmaf((acc[t][r] - mu) * rs, g4[t][r], be4[t][r]);
      ((short*)&s)[r] = bfb(fmaxf(v, 0.f));
    }
    *(short4*)(Aw + (tb + col) * ASTR + t * 16 + quad * 4) = s;
  }
}

template <int NT>
__device__ __forceinline__ void plainT_write(short* Aw, int tb, int col,
                                             int quad, v4f* acc) {
#pragma unroll
  for (int t = 0; t < NT; ++t) {
    short4 s;
#pragma unroll
    for (int r = 0; r < 4; ++r) ((short*)&s)[r] = bfb(acc[t][r]);
    *(short4*)(Aw + (tb + col) * ASTR + t * 16 + quad * 4) = s;
  }
}

// ---- kF: the whole network, one wave = 4 clusters, zero barriers ----
// Round-0 body; 2-wave blocks; launch_bounds second arg = 2 (no VGPR cap).
__global__ void __launch_bounds__(128, 2)
kF(const float* __restrict__ x, const int* __restrict__ batch,
   const short* __restrict__ wsW,
   const float* __restrict__ pb1, const float* __restrict__ pg,
   const float* __restrict__ pbe, const float* __restrict__ pb2,
   const float* __restrict__ b1a, const float* __restrict__ ga,
   const float* __restrict__ bea, const float* __restrict__ b2a,
   const float* __restrict__ b1b, const float* __restrict__ gb,
   const float* __restrict__ beb, const float* __restrict__ b2b,
   const float* __restrict__ b1c, const float* __restrict__ gc_,
   const float* __restrict__ bec, const float* __restrict__ b2c,
   const float* __restrict__ ob1, const float* __restrict__ og,
   const float* __restrict__ obe, const float* __restrict__ ob2,
   float* __restrict__ out, int C) {
  __shared__ __align__(16) short act[2 * 80 * ASTR];   // 23040 B
  const int tid = threadIdx.x;
  const int lane = tid & 63;
  const int wave = tid >> 6;
  const int col = lane & 15;
  const int quad = lane >> 4;
  const int cbase = blockIdx.x * 8 + wave * 4;
  if (cbase >= C) return;
  const int nc = min(4, C - cbase);
  const int nrows = nc * 20;
  const int ntiles = (nrows + 15) >> 4;
  short* A = act + wave * 80 * ASTR;

  // ---- load x -> bf16 cols 0..15, zero cols 16..31 ----
  {
    const float4* x4 = (const float4*)x;
    const long nb = (long)cbase * 20;
    const short4 z = {0, 0, 0, 0};
    for (int i = lane; i < nrows * 4; i += 64) {
      const int row = i >> 2, e = i & 3;
      float4 v = x4[(nb + row) * 4 + e];
      short4 s = {bfb(v.x), bfb(v.y), bfb(v.z), bfb(v.w)};
      *(short4*)(A + row * ASTR + e * 4) = s;
      *(short4*)(A + row * ASTR + 16 + e * 4) = z;
    }
    if (nrows < ntiles * 16) {
      for (int i = lane; i < (ntiles * 16 - nrows) * 18; i += 64) {
        const int row = nrows + i / 18, e = i % 18;
        *(short4*)(A + row * ASTR + e * 4) = z;
      }
    }
  }

  // ---- pre-MLP stage 1: 16(pad32) -> 64, LN, ReLU ----
  {
    v8s Wf[4]; v4f b4[4], g4[4], be4[4];
#pragma unroll
    for (int t = 0; t < 4; ++t) {
      Wf[t] = *(const v8s*)(wsW + OFF_PW1 + (t * 16 + col) * 32 + quad * 8);
      b4[t]  = *(const v4f*)(pb1 + t * 16 + quad * 4);
      g4[t]  = *(const v4f*)(pg  + t * 16 + quad * 4);
      be4[t] = *(const v4f*)(pbe + t * 16 + quad * 4);
    }
    for (int T = 0; T < ntiles; ++T) {
      v4f acc[4];
      mmT<4, 1>(A, T * 16, Wf, b4, col, quad, acc);
      lnT_write(A, T * 16, col, quad, acc, g4, be4);
    }
  }

  // ---- pre-MLP stage 2: 64 -> 64 (no LN) ----
  {
    v8s Wf[8]; v4f b4[4];
#pragma unroll
    for (int t = 0; t < 4; ++t) {
#pragma unroll
      for (int ks = 0; ks < 2; ++ks)
        Wf[t * 2 + ks] = *(const v8s*)(wsW + OFF_PW2 + (t * 16 + col) * 64 + ks * 32 + quad * 8);
      b4[t] = *(const v4f*)(pb2 + t * 16 + quad * 4);
    }
    for (int T = 0; T < ntiles; ++T) {
      v4f acc[4];
      mmT<4, 2>(A, T * 16, Wf, b4, col, quad, acc);
      plainT_write<4>(A, T * 16, col, quad, acc);
    }
  }

  // ---- 3 subgraph layers ----
  const float* B1p[3] = {b1a, b1b, b1c};
  const float* Gp[3]  = {ga, gb, gc_};
  const float* BEp[3] = {bea, beb, bec};
  const float* B2p[3] = {b2a, b2b, b2c};

  for (int L = 0; L < 3; ++L) {
    v8s W1f[8], W2f[4];
    v4f b14[4], g4[4], be4[4], b24[2];
    const short* w1 = wsW + OFF_LW1(L);
    const short* w2 = wsW + OFF_LW2(L);
#pragma unroll
    for (int t = 0; t < 4; ++t) {
#pragma unroll
      for (int ks = 0; ks < 2; ++ks)
        W1f[t * 2 + ks] = *(const v8s*)(w1 + (t * 16 + col) * 64 + ks * 32 + quad * 8);
      b14[t] = *(const v4f*)(B1p[L] + t * 16 + quad * 4);
      g4[t]  = *(const v4f*)(Gp[L]  + t * 16 + quad * 4);
      be4[t] = *(const v4f*)(BEp[L] + t * 16 + quad * 4);
    }
#pragma unroll
    for (int t = 0; t < 2; ++t) {
#pragma unroll
      for (int ks = 0; ks < 2; ++ks)
        W2f[t * 2 + ks] = *(const v8s*)(w2 + (t * 16 + col) * 64 + ks * 32 + quad * 8);
      b24[t] = *(const v4f*)(B2p[L] + t * 16 + quad * 4);
    }
    for (int T = 0; T < ntiles; ++T) {
      v4f acc[4];
      mmT<4, 2>(A, T * 16, W1f, b14, col, quad, acc);
      lnT_write(A, T * 16, col, quad, acc, g4, be4);
      v4f h[2];
      mmT<2, 2>(A, T * 16, W2f, b24, col, quad, h);
      plainT_write<2>(A, T * 16, col, quad, h);
    }
    // ---- intra-wave pooling: 4 clusters x 16 uint-cols ----
    {
      const int cl = quad, jp = col;
      if (cl < nc) {
        const uint* AU = (const uint*)A;
        float m0 = -3.4e38f, m1 = -3.4e38f;
#pragma unroll
        for (int r = 0; r < 20; ++r) {
          const uint v = AU[(cl * 20 + r) * (ASTR / 2) + jp];
          m0 = fmaxf(m0, __builtin_bit_cast(float, v << 16));
          m1 = fmaxf(m1, __builtin_bit_cast(float, v & 0xFFFF0000u));
        }
        const uint pv = (uint)(unsigned short)bfb(m0) |
                        ((uint)(unsigned short)bfb(m1) << 16);
        uint* AW = (uint*)A;
        if (L < 2) {
#pragma unroll
          for (int r = 0; r < 20; ++r)
            AW[(cl * 20 + r) * (ASTR / 2) + 16 + jp] = pv;
        } else {
          // segmax(concat[h,pooled]) == [pooled,pooled] -> rows 0..3 = pooled
          AW[cl * (ASTR / 2) + jp] = pv;
          AW[cl * (ASTR / 2) + 16 + jp] = pv;
        }
      }
    }
  }

  // ---- fused output MLP on rows 0..15 (rows 0..nc-1 valid) ----
  {
    v8s Wf[8]; v4f b4[4], g4[4], be4[4];
#pragma unroll
    for (int t = 0; t < 4; ++t) {
#pragma unroll
      for (int ks = 0; ks < 2; ++ks)
        Wf[t * 2 + ks] = *(const v8s*)(wsW + OFF_OW1 + (t * 16 + col) * 64 + ks * 32 + quad * 8);
      b4[t]  = *(const v4f*)(ob1 + t * 16 + quad * 4);
      g4[t]  = *(const v4f*)(og  + t * 16 + quad * 4);
      be4[t] = *(const v4f*)(obe + t * 16 + quad * 4);
    }
    v4f acc[4];
    mmT<4, 2>(A, 0, Wf, b4, col, quad, acc);
    lnT_write(A, 0, col, quad, acc, g4, be4);
  }
  {
    v4f acc[8];
    const v8s bb0 = *(const v8s*)(A + col * ASTR + quad * 8);
    const v8s bb1 = *(const v8s*)(A + col * ASTR + 32 + quad * 8);
#pragma unroll
    for (int half = 0; half < 2; ++half) {
      v8s Wf[8];
#pragma unroll
      for (int t = 0; t < 4; ++t)
#pragma unroll
        for (int ks = 0; ks < 2; ++ks)
          Wf[t * 2 + ks] = *(const v8s*)(wsW + OFF_OW2 +
                             ((half * 4 + t) * 16 + col) * 64 + ks * 32 + quad * 8);
#pragma unroll
      for (int t = 0; t < 4; ++t) {
        v4f a = *(const v4f*)(ob2 + (half * 4 + t) * 16 + quad * 4);
        a = MFMA(Wf[t * 2], bb0, a, 0, 0, 0);
        a = MFMA(Wf[t * 2 + 1], bb1, a, 0, 0, 0);
        acc[half * 4 + t] = a;
      }
    }
    // L2 norm over 128 feats (32 in-lane + cross-quad)
    float sq = 0.f;
#pragma unroll
    for (int t = 0; t < 8; ++t)
#pragma unroll
      for (int r = 0; r < 4; ++r) sq = fmaf(acc[t][r], acc[t][r], sq);
    sq += __shfl_xor(sq, 16); sq += __shfl_xor(sq, 32);
    const float inv = 1.0f / fmaxf(sqrtf(sq), 1e-12f);
    if (col < nc) {
      const long gcl = cbase + col;
#pragma unroll
      for (int t = 0; t < 8; ++t) {
        float4 v = {acc[t][0] * inv, acc[t][1] * inv,
                    acc[t][2] * inv, acc[t][3] * inv};
        *(float4*)(out + gcl * 128 + t * 16 + quad * 4) = v;
      }
      if (quad == 0) out[(long)C * 128 + gcl] = (float)batch[gcl * 20];
    }
  }
}

extern "C" void kernel_launch(void* const* d_in, const int* in_sizes, int n_in,
                              void* d_out, int out_size, void* d_ws, size_t ws_size,
                              hipStream_t stream) {
  const float* x     = (const float*)d_in[0];
  const int*   batch = (const int*)d_in[2];
  const float* pw1 = (const float*)d_in[3];
  const float* pb1 = (const float*)d_in[4];
  const float* pg  = (const float*)d_in[5];
  const float* pbe = (const float*)d_in[6];
  const float* pw2 = (const float*)d_in[7];
  const float* pb2 = (const float*)d_in[8];
  const float* w1a = (const float*)d_in[9];
  const float* b1a = (const float*)d_in[10];
  const float* ga  = (const float*)d_in[11];
  const float* bea = (const float*)d_in[12];
  const float* w2a = (const float*)d_in[13];
  const float* b2a = (const float*)d_in[14];
  const float* w1b = (const float*)d_in[15];
  const float* b1b = (const float*)d_in[16];
  const float* gb  = (const float*)d_in[17];
  const float* beb = (const float*)d_in[18];
  const float* w2b = (const float*)d_in[19];
  const float* b2b = (const float*)d_in[20];
  const float* w1c = (const float*)d_in[21];
  const float* b1c = (const float*)d_in[22];
  const float* gc  = (const float*)d_in[23];
  const float* bec = (const float*)d_in[24];
  const float* w2c = (const float*)d_in[25];
  const float* b2c = (const float*)d_in[26];
  const float* ow1 = (const float*)d_in[27];
  const float* ob1 = (const float*)d_in[28];
  const float* og  = (const float*)d_in[29];
  const float* obe = (const float*)d_in[30];
  const float* ow2 = (const float*)d_in[31];
  const float* ob2 = (const float*)d_in[32];

  const int N = in_sizes[0] / 16;
  const int C = N / 20;
  short* ws16 = (short*)d_ws;
  float* out = (float*)d_out;

  hipLaunchKernelGGL(kT, dim3(10), dim3(256), 0, stream,
                     pw1, pw2, w1a, w2a, w1b, w2b, w1c, w2c, ow1, ow2, ws16);

  const int blocks = (C + 7) / 8;   // 8 clusters per block (2 waves x 4)
  hipLaunchKernelGGL(kF, dim3(blocks), dim3(128), 0, stream,
                     x, batch, (const short*)ws16,
                     pb1, pg, pbe, pb2,
                     b1a, ga, bea, b2a,
                     b1b, gb, beb, b2b,
                     b1c, gc, bec, b2c,
                     ob1, og, obe, ob2,
                     out, C);
}

// Round 9
// 307.739 us; speedup vs baseline: 1.2884x; 1.0043x over previous
//
#include <hip/hip_runtime.h>

// ---------------------------------------------------------------------------
// Barrier-free wave-autonomous design, TRANSPOSED MFMA epilogue.
// Round 9 = round 8 resubmit (R8: container failed twice, no profile; same
// infra signature as R1/R2). One defensive fix: R8 stored the fused bias at
// OFF_FB=36864 shorts — 256 B PAST the workspace footprint every passing
// kernel used ([0,36864) shorts). If ws_size is tight, that write was OOB ->
// GPU fault -> container death. Fused bias now lives in the OFF_PW2 slot
// (2048..6144, unused after fusion): footprint back to the historical range.
// The optimization itself (unchanged from R8): pre-MLP Linear#2 (no
// activation) fused with layer-0 W1:  z = y1 @ (pw2@w1a) + (pb2@w1a + b1a).
// kT computes fused weight (fp32 accum -> bf16, into LW1(0)) and fused bias
// (f32 at OFF_PW2); kF deletes the pre2 stage: -40 MFMA, -5 pack/write
// passes, -30 DS ops, -1 LDS round-trip per wave. Base: validated R7 shape
// (128-thr blocks, launch_bounds(128,2), runtime tile loops, zero scratch).
// ---------------------------------------------------------------------------

#define ASTR 72   // act row stride in shorts

typedef short v8s __attribute__((ext_vector_type(8)));
typedef float v4f __attribute__((ext_vector_type(4)));

#define MFMA __builtin_amdgcn_mfma_f32_16x16x32_bf16

// ws layout (offsets in shorts)
#define OFF_PW1 0                        // 64 x 32 (K=16 zero-padded to 32)
#define OFF_FB  2048                     // 64 f32 fused bias (in old PW2 slot)
#define OFF_LW1(L) (6144 + (L) * 6144)   // 64 x 64  (L=0 holds FUSED pw2@w1a)
#define OFF_LW2(L) (OFF_LW1(L) + 4096)   // 32 x 64
#define OFF_OW1 24576                    // 64 x 64
#define OFF_OW2 28672                    // 128 x 64   (end = 36864 shorts)

__device__ __forceinline__ short bfb(float v) {
  __bf16 b = (__bf16)v;
  return __builtin_bit_cast(short, b);
}

// ---- kT: transpose weights into bf16 B-fragment layout in ws ----
// block 1: fused bias pb2@w1a + b1a (f32 -> OFF_FB)
// block 2: fused weight pw2@w1a (fp32 accum -> bf16 fragments -> LW1(0))
__global__ void kT(const float* __restrict__ pw1, const float* __restrict__ pw2,
                   const float* __restrict__ w1a, const float* __restrict__ w2a,
                   const float* __restrict__ w1b, const float* __restrict__ w2b,
                   const float* __restrict__ w1c, const float* __restrict__ w2c,
                   const float* __restrict__ ow1, const float* __restrict__ ow2,
                   const float* __restrict__ pb2, const float* __restrict__ b1a,
                   short* __restrict__ ws) {
  if (blockIdx.x == 1) {
    // fused bias: fb[f] = sum_m pb2[m] * w1a[m*64+f] + b1a[f]
    float* fb = (float*)(ws + OFF_FB);
    for (int f = threadIdx.x; f < 64; f += blockDim.x) {
      float s = b1a[f];
      for (int m = 0; m < 64; ++m) s = fmaf(pb2[m], w1a[m * 64 + f], s);
      fb[f] = s;
    }
    return;
  }
  if (blockIdx.x == 2) {
    // fused weight: Wf[k][f] = sum_m pw2[k*64+m] * w1a[m*64+f]
    const int off = OFF_LW1(0);
    const int total = 64 * 8;   // F=64, Kpad=64 -> 8 v8s per f
    for (int i = threadIdx.x; i < total; i += blockDim.x) {
      const int f = i % 64;
      const int kq = i / 64;
      v8s h;
#pragma unroll
      for (int j = 0; j < 8; ++j) {
        const int k = kq * 8 + j;
        float s = 0.f;
        for (int m = 0; m < 64; ++m) s = fmaf(pw2[k * 64 + m], w1a[m * 64 + f], s);
        h[j] = bfb(s);
      }
      *(v8s*)(ws + off + f * 64 + kq * 8) = h;
    }
    return;
  }
  const float* W; int K, F, Kpad, off;
  switch (blockIdx.x) {
    case 0: W = pw1; K = 16; F = 64;  Kpad = 32; off = OFF_PW1; break;
    case 3: W = w2a; K = 64; F = 32;  Kpad = 64; off = OFF_LW2(0); break;
    case 4: W = w1b; K = 64; F = 64;  Kpad = 64; off = OFF_LW1(1); break;
    case 5: W = w2b; K = 64; F = 32;  Kpad = 64; off = OFF_LW2(1); break;
    case 6: W = w1c; K = 64; F = 64;  Kpad = 64; off = OFF_LW1(2); break;
    case 7: W = w2c; K = 64; F = 32;  Kpad = 64; off = OFF_LW2(2); break;
    case 8: W = ow1; K = 64; F = 64;  Kpad = 64; off = OFF_OW1; break;
    default: W = ow2; K = 64; F = 128; Kpad = 64; off = OFF_OW2; break;
  }
  const int total = F * (Kpad >> 3);
  for (int i = threadIdx.x; i < total; i += blockDim.x) {
    const int f = i % F;
    const int kq = i / F;
    v8s h;
#pragma unroll
    for (int j = 0; j < 8; ++j) {
      const int k = kq * 8 + j;
      h[j] = bfb((k < K) ? W[k * F + f] : 0.f);
    }
    *(v8s*)(ws + off + f * Kpad + kq * 8) = h;
  }
}

// Transposed matmul over one 16-node tile: acc[t] covers features t*16..+15.
template <int NT, int KS>
__device__ __forceinline__ void mmT(const short* A, int tb, const v8s* Wf,
                                    const v4f* bias4, int col, int quad,
                                    v4f* acc) {
#pragma unroll
  for (int t = 0; t < NT; ++t) acc[t] = bias4[t];
#pragma unroll
  for (int ks = 0; ks < KS; ++ks) {
    const v8s b = *(const v8s*)(A + (tb + col) * ASTR + ks * 32 + quad * 8);
#pragma unroll
    for (int t = 0; t < NT; ++t)
      acc[t] = MFMA(Wf[t * KS + ks], b, acc[t], 0, 0, 0);
  }
}

// LayerNorm(64)+ReLU, features in-lane; short4 (b64) writes.
__device__ __forceinline__ void lnT_write(short* Aw, int tb, int col, int quad,
                                          v4f* acc, const v4f* g4,
                                          const v4f* be4) {
  float mu = 0.f, sq = 0.f;
#pragma unroll
  for (int t = 0; t < 4; ++t)
#pragma unroll
    for (int r = 0; r < 4; ++r) {
      mu += acc[t][r];
      sq = fmaf(acc[t][r], acc[t][r], sq);
    }
  mu += __shfl_xor(mu, 16); mu += __shfl_xor(mu, 32);
  sq += __shfl_xor(sq, 16); sq += __shfl_xor(sq, 32);
  mu *= (1.0f / 64.0f);
  const float var = sq * (1.0f / 64.0f) - mu * mu;
  const float rs = rsqrtf(var + 1e-5f);
#pragma unroll
  for (int t = 0; t < 4; ++t) {
    short4 s;
#pragma unroll
    for (int r = 0; r < 4; ++r) {
      float v = fmaf((acc[t][r] - mu) * rs, g4[t][r], be4[t][r]);
      ((short*)&s)[r] = bfb(fmaxf(v, 0.f));
    }
    *(short4*)(Aw + (tb + col) * ASTR + t * 16 + quad * 4) = s;
  }
}

template <int NT>
__device__ __forceinline__ void plainT_write(short* Aw, int tb, int col,
                                             int quad, v4f* acc) {
#pragma unroll
  for (int t = 0; t < NT; ++t) {
    short4 s;
#pragma unroll
    for (int r = 0; r < 4; ++r) ((short*)&s)[r] = bfb(acc[t][r]);
    *(short4*)(Aw + (tb + col) * ASTR + t * 16 + quad * 4) = s;
  }
}

// ---- kF: the whole network, one wave = 4 clusters, zero barriers ----
__global__ void __launch_bounds__(128, 2)
kF(const float* __restrict__ x, const int* __restrict__ batch,
   const short* __restrict__ wsW,
   const float* __restrict__ pb1, const float* __restrict__ pg,
   const float* __restrict__ pbe,
   const float* __restrict__ b1a, const float* __restrict__ ga,
   const float* __restrict__ bea, const float* __restrict__ b2a,
   const float* __restrict__ b1b, const float* __restrict__ gb,
   const float* __restrict__ beb, const float* __restrict__ b2b,
   const float* __restrict__ b1c, const float* __restrict__ gc_,
   const float* __restrict__ bec, const float* __restrict__ b2c,
   const float* __restrict__ ob1, const float* __restrict__ og,
   const float* __restrict__ obe, const float* __restrict__ ob2,
   float* __restrict__ out, int C) {
  __shared__ __align__(16) short act[2 * 80 * ASTR];   // 23040 B
  const int tid = threadIdx.x;
  const int lane = tid & 63;
  const int wave = tid >> 6;
  const int col = lane & 15;
  const int quad = lane >> 4;
  const int cbase = blockIdx.x * 8 + wave * 4;
  if (cbase >= C) return;
  const int nc = min(4, C - cbase);
  const int nrows = nc * 20;
  const int ntiles = (nrows + 15) >> 4;
  short* A = act + wave * 80 * ASTR;

  // ---- load x -> bf16 cols 0..15, zero cols 16..31 ----
  {
    const float4* x4 = (const float4*)x;
    const long nb = (long)cbase * 20;
    const short4 z = {0, 0, 0, 0};
    for (int i = lane; i < nrows * 4; i += 64) {
      const int row = i >> 2, e = i & 3;
      float4 v = x4[(nb + row) * 4 + e];
      short4 s = {bfb(v.x), bfb(v.y), bfb(v.z), bfb(v.w)};
      *(short4*)(A + row * ASTR + e * 4) = s;
      *(short4*)(A + row * ASTR + 16 + e * 4) = z;
    }
    if (nrows < ntiles * 16) {
      for (int i = lane; i < (ntiles * 16 - nrows) * 18; i += 64) {
        const int row = nrows + i / 18, e = i % 18;
        *(short4*)(A + row * ASTR + e * 4) = z;
      }
    }
  }

  // ---- pre-MLP stage 1: 16(pad32) -> 64, LN, ReLU  (y1 into rows) ----
  {
    v8s Wf[4]; v4f b4[4], g4[4], be4[4];
#pragma unroll
    for (int t = 0; t < 4; ++t) {
      Wf[t] = *(const v8s*)(wsW + OFF_PW1 + (t * 16 + col) * 32 + quad * 8);
      b4[t]  = *(const v4f*)(pb1 + t * 16 + quad * 4);
      g4[t]  = *(const v4f*)(pg  + t * 16 + quad * 4);
      be4[t] = *(const v4f*)(pbe + t * 16 + quad * 4);
    }
    for (int T = 0; T < ntiles; ++T) {
      v4f acc[4];
      mmT<4, 1>(A, T * 16, Wf, b4, col, quad, acc);
      lnT_write(A, T * 16, col, quad, acc, g4, be4);
    }
  }

  // (pre-MLP stage 2 fused into layer 0's W1 -- see kT blocks 1/2)

  // ---- 3 subgraph layers ----
  const float* fb = (const float*)(wsW + OFF_FB);   // fused bias for L0-W1
  const float* B1p[3] = {fb, b1b, b1c};
  const float* Gp[3]  = {ga, gb, gc_};
  const float* BEp[3] = {bea, beb, bec};
  const float* B2p[3] = {b2a, b2b, b2c};

  for (int L = 0; L < 3; ++L) {
    v8s W1f[8], W2f[4];
    v4f b14[4], g4[4], be4[4], b24[2];
    const short* w1 = wsW + OFF_LW1(L);
    const short* w2 = wsW + OFF_LW2(L);
#pragma unroll
    for (int t = 0; t < 4; ++t) {
#pragma unroll
      for (int ks = 0; ks < 2; ++ks)
        W1f[t * 2 + ks] = *(const v8s*)(w1 + (t * 16 + col) * 64 + ks * 32 + quad * 8);
      b14[t] = *(const v4f*)(B1p[L] + t * 16 + quad * 4);
      g4[t]  = *(const v4f*)(Gp[L]  + t * 16 + quad * 4);
      be4[t] = *(const v4f*)(BEp[L] + t * 16 + quad * 4);
    }
#pragma unroll
    for (int t = 0; t < 2; ++t) {
#pragma unroll
      for (int ks = 0; ks < 2; ++ks)
        W2f[t * 2 + ks] = *(const v8s*)(w2 + (t * 16 + col) * 64 + ks * 32 + quad * 8);
      b24[t] = *(const v4f*)(B2p[L] + t * 16 + quad * 4);
    }
    for (int T = 0; T < ntiles; ++T) {
      v4f acc[4];
      mmT<4, 2>(A, T * 16, W1f, b14, col, quad, acc);
      lnT_write(A, T * 16, col, quad, acc, g4, be4);
      v4f h[2];
      mmT<2, 2>(A, T * 16, W2f, b24, col, quad, h);
      plainT_write<2>(A, T * 16, col, quad, h);
    }
    // ---- intra-wave pooling: 4 clusters x 16 uint-cols ----
    {
      const int cl = quad, jp = col;
      if (cl < nc) {
        const uint* AU = (const uint*)A;
        float m0 = -3.4e38f, m1 = -3.4e38f;
#pragma unroll
        for (int r = 0; r < 20; ++r) {
          const uint v = AU[(cl * 20 + r) * (ASTR / 2) + jp];
          m0 = fmaxf(m0, __builtin_bit_cast(float, v << 16));
          m1 = fmaxf(m1, __builtin_bit_cast(float, v & 0xFFFF0000u));
        }
        const uint pv = (uint)(unsigned short)bfb(m0) |
                        ((uint)(unsigned short)bfb(m1) << 16);
        uint* AW = (uint*)A;
        if (L < 2) {
#pragma unroll
          for (int r = 0; r < 20; ++r)
            AW[(cl * 20 + r) * (ASTR / 2) + 16 + jp] = pv;
        } else {
          // segmax(concat[h,pooled]) == [pooled,pooled] -> rows 0..3 = pooled
          AW[cl * (ASTR / 2) + jp] = pv;
          AW[cl * (ASTR / 2) + 16 + jp] = pv;
        }
      }
    }
  }

  // ---- fused output MLP on rows 0..15 (rows 0..nc-1 valid) ----
  {
    v8s Wf[8]; v4f b4[4], g4[4], be4[4];
#pragma unroll
    for (int t = 0; t < 4; ++t) {
#pragma unroll
      for (int ks = 0; ks < 2; ++ks)
        Wf[t * 2 + ks] = *(const v8s*)(wsW + OFF_OW1 + (t * 16 + col) * 64 + ks * 32 + quad * 8);
      b4[t]  = *(const v4f*)(ob1 + t * 16 + quad * 4);
      g4[t]  = *(const v4f*)(og  + t * 16 + quad * 4);
      be4[t] = *(const v4f*)(obe + t * 16 + quad * 4);
    }
    v4f acc[4];
    mmT<4, 2>(A, 0, Wf, b4, col, quad, acc);
    lnT_write(A, 0, col, quad, acc, g4, be4);
  }
  {
    v4f acc[8];
    const v8s bb0 = *(const v8s*)(A + col * ASTR + quad * 8);
    const v8s bb1 = *(const v8s*)(A + col * ASTR + 32 + quad * 8);
#pragma unroll
    for (int half = 0; half < 2; ++half) {
      v8s Wf[8];
#pragma unroll
      for (int t = 0; t < 4; ++t)
#pragma unroll
        for (int ks = 0; ks < 2; ++ks)
          Wf[t * 2 + ks] = *(const v8s*)(wsW + OFF_OW2 +
                             ((half * 4 + t) * 16 + col) * 64 + ks * 32 + quad * 8);
#pragma unroll
      for (int t = 0; t < 4; ++t) {
        v4f a = *(const v4f*)(ob2 + (half * 4 + t) * 16 + quad * 4);
        a = MFMA(Wf[t * 2], bb0, a, 0, 0, 0);
        a = MFMA(Wf[t * 2 + 1], bb1, a, 0, 0, 0);
        acc[half * 4 + t] = a;
      }
    }
    // L2 norm over 128 feats (32 in-lane + cross-quad)
    float sq = 0.f;
#pragma unroll
    for (int t = 0; t < 8; ++t)
#pragma unroll
      for (int r = 0; r < 4; ++r) sq = fmaf(acc[t][r], acc[t][r], sq);
    sq += __shfl_xor(sq, 16); sq += __shfl_xor(sq, 32);
    const float inv = 1.0f / fmaxf(sqrtf(sq), 1e-12f);
    if (col < nc) {
      const long gcl = cbase + col;
#pragma unroll
      for (int t = 0; t < 8; ++t) {
        float4 v = {acc[t][0] * inv, acc[t][1] * inv,
                    acc[t][2] * inv, acc[t][3] * inv};
        *(float4*)(out + gcl * 128 + t * 16 + quad * 4) = v;
      }
      if (quad == 0) out[(long)C * 128 + gcl] = (float)batch[gcl * 20];
    }
  }
}

extern "C" void kernel_launch(void* const* d_in, const int* in_sizes, int n_in,
                              void* d_out, int out_size, void* d_ws, size_t ws_size,
                              hipStream_t stream) {
  const float* x     = (const float*)d_in[0];
  const int*   batch = (const int*)d_in[2];
  const float* pw1 = (const float*)d_in[3];
  const float* pb1 = (const float*)d_in[4];
  const float* pg  = (const float*)d_in[5];
  const float* pbe = (const float*)d_in[6];
  const float* pw2 = (const float*)d_in[7];
  const float* pb2 = (const float*)d_in[8];
  const float* w1a = (const float*)d_in[9];
  const float* b1a = (const float*)d_in[10];
  const float* ga  = (const float*)d_in[11];
  const float* bea = (const float*)d_in[12];
  const float* w2a = (const float*)d_in[13];
  const float* b2a = (const float*)d_in[14];
  const float* w1b = (const float*)d_in[15];
  const float* b1b = (const float*)d_in[16];
  const float* gb  = (const float*)d_in[17];
  const float* beb = (const float*)d_in[18];
  const float* w2b = (const float*)d_in[19];
  const float* b2b = (const float*)d_in[20];
  const float* w1c = (const float*)d_in[21];
  const float* b1c = (const float*)d_in[22];
  const float* gc  = (const float*)d_in[23];
  const float* bec = (const float*)d_in[24];
  const float* w2c = (const float*)d_in[25];
  const float* b2c = (const float*)d_in[26];
  const float* ow1 = (const float*)d_in[27];
  const float* ob1 = (const float*)d_in[28];
  const float* og  = (const float*)d_in[29];
  const float* obe = (const float*)d_in[30];
  const float* ow2 = (const float*)d_in[31];
  const float* ob2 = (const float*)d_in[32];

  const int N = in_sizes[0] / 16;
  const int C = N / 20;
  short* ws16 = (short*)d_ws;
  float* out = (float*)d_out;

  hipLaunchKernelGGL(kT, dim3(10), dim3(256), 0, stream,
                     pw1, pw2, w1a, w2a, w1b, w2b, w1c, w2c, ow1, ow2,
                     pb2, b1a, ws16);

  const int blocks = (C + 7) / 8;   // 8 clusters per block (2 waves x 4)
  hipLaunchKernelGGL(kF, dim3(blocks), dim3(128), 0, stream,
                     x, batch, (const short*)ws16,
                     pb1, pg, pbe,
                     b1a, ga, bea, b2a,
                     b1b, gb, beb, b2b,
                     b1c, gc, bec, b2c,
                     ob1, og, obe, ob2,
                     out, C);
}

// Round 12
// 303.068 us; speedup vs baseline: 1.3082x; 1.0154x over previous
//
#include <hip/hip_runtime.h>

// ---------------------------------------------------------------------------
// Barrier-free wave-autonomous design, TRANSPOSED MFMA epilogue.
// Round 12: de-bundle after R10/R11 failed twice (pre-committed plan).
// Base = R9 exactly (pre2<>L0W1 fusion, 159us kF, zero scratch, passed),
// plus ONLY change (B) — both halves of which ran verbatim in R5's PASSING
// kernel:
//  (B) compact pooled buffer in the row padding (cols 64..71 of rows 0..15):
//      layers 0/1 write pooled max ONCE per lane (was 20 broadcast
//      ds_write_b32); layers 1/2 read the k=32..63 B-fragment from the pad
//      as a broadcast ds_read_b128 (<=2 distinct addrs per tile).
// Change (F) (reg-zero pre1 B-operand, never hardware-validated) is DROPPED:
// x-load zero-fill and pre-MLP stage 1 are byte-identical to R9. L-loop
// keeps R9's array-of-pointers form (proven scratch-free, VGPR 76).
// ---------------------------------------------------------------------------

#define ASTR 72   // act row stride in shorts (64 feats + 8 pad = pooled slot)

typedef short v8s __attribute__((ext_vector_type(8)));
typedef float v4f __attribute__((ext_vector_type(4)));

#define MFMA __builtin_amdgcn_mfma_f32_16x16x32_bf16

// ws layout (offsets in shorts)
#define OFF_PW1 0                        // 64 x 32 (K=16 zero-padded to 32)
#define OFF_FB  2048                     // 64 f32 fused bias (in old PW2 slot)
#define OFF_LW1(L) (6144 + (L) * 6144)   // 64 x 64  (L=0 holds FUSED pw2@w1a)
#define OFF_LW2(L) (OFF_LW1(L) + 4096)   // 32 x 64
#define OFF_OW1 24576                    // 64 x 64
#define OFF_OW2 28672                    // 128 x 64   (end = 36864 shorts)

__device__ __forceinline__ short bfb(float v) {
  __bf16 b = (__bf16)v;
  return __builtin_bit_cast(short, b);
}

// ---- kT: transpose weights into bf16 B-fragment layout in ws ----
// block 1: fused bias pb2@w1a + b1a (f32 -> OFF_FB)
// block 2: fused weight pw2@w1a (fp32 accum -> bf16 fragments -> LW1(0))
__global__ void kT(const float* __restrict__ pw1, const float* __restrict__ pw2,
                   const float* __restrict__ w1a, const float* __restrict__ w2a,
                   const float* __restrict__ w1b, const float* __restrict__ w2b,
                   const float* __restrict__ w1c, const float* __restrict__ w2c,
                   const float* __restrict__ ow1, const float* __restrict__ ow2,
                   const float* __restrict__ pb2, const float* __restrict__ b1a,
                   short* __restrict__ ws) {
  if (blockIdx.x == 1) {
    // fused bias: fb[f] = sum_m pb2[m] * w1a[m*64+f] + b1a[f]
    float* fb = (float*)(ws + OFF_FB);
    for (int f = threadIdx.x; f < 64; f += blockDim.x) {
      float s = b1a[f];
      for (int m = 0; m < 64; ++m) s = fmaf(pb2[m], w1a[m * 64 + f], s);
      fb[f] = s;
    }
    return;
  }
  if (blockIdx.x == 2) {
    // fused weight: Wf[k][f] = sum_m pw2[k*64+m] * w1a[m*64+f]
    const int off = OFF_LW1(0);
    const int total = 64 * 8;   // F=64, Kpad=64 -> 8 v8s per f
    for (int i = threadIdx.x; i < total; i += blockDim.x) {
      const int f = i % 64;
      const int kq = i / 64;
      v8s h;
#pragma unroll
      for (int j = 0; j < 8; ++j) {
        const int k = kq * 8 + j;
        float s = 0.f;
        for (int m = 0; m < 64; ++m) s = fmaf(pw2[k * 64 + m], w1a[m * 64 + f], s);
        h[j] = bfb(s);
      }
      *(v8s*)(ws + off + f * 64 + kq * 8) = h;
    }
    return;
  }
  const float* W; int K, F, Kpad, off;
  switch (blockIdx.x) {
    case 0: W = pw1; K = 16; F = 64;  Kpad = 32; off = OFF_PW1; break;
    case 3: W = w2a; K = 64; F = 32;  Kpad = 64; off = OFF_LW2(0); break;
    case 4: W = w1b; K = 64; F = 64;  Kpad = 64; off = OFF_LW1(1); break;
    case 5: W = w2b; K = 64; F = 32;  Kpad = 64; off = OFF_LW2(1); break;
    case 6: W = w1c; K = 64; F = 64;  Kpad = 64; off = OFF_LW1(2); break;
    case 7: W = w2c; K = 64; F = 32;  Kpad = 64; off = OFF_LW2(2); break;
    case 8: W = ow1; K = 64; F = 64;  Kpad = 64; off = OFF_OW1; break;
    default: W = ow2; K = 64; F = 128; Kpad = 64; off = OFF_OW2; break;
  }
  const int total = F * (Kpad >> 3);
  for (int i = threadIdx.x; i < total; i += blockDim.x) {
    const int f = i % F;
    const int kq = i / F;
    v8s h;
#pragma unroll
    for (int j = 0; j < 8; ++j) {
      const int k = kq * 8 + j;
      h[j] = bfb((k < K) ? W[k * F + f] : 0.f);
    }
    *(v8s*)(ws + off + f * Kpad + kq * 8) = h;
  }
}

// Transposed matmul over one 16-node tile: acc[t] covers features t*16..+15.
template <int NT, int KS>
__device__ __forceinline__ void mmT(const short* A, int tb, const v8s* Wf,
                                    const v4f* bias4, int col, int quad,
                                    v4f* acc) {
#pragma unroll
  for (int t = 0; t < NT; ++t) acc[t] = bias4[t];
#pragma unroll
  for (int ks = 0; ks < KS; ++ks) {
    const v8s b = *(const v8s*)(A + (tb + col) * ASTR + ks * 32 + quad * 8);
#pragma unroll
    for (int t = 0; t < NT; ++t)
      acc[t] = MFMA(Wf[t * KS + ks], b, acc[t], 0, 0, 0);
  }
}

// Split matmul: k=0..31 from act row (h), k=32..63 from pooled pad (bcast).
// (both the pad write and this read ran verbatim in R5's passing kernel)
template <int NT>
__device__ __forceinline__ void mmT_split(const short* A, int tb,
                                          const v8s* Wf, const v4f* bias4,
                                          int col, int quad, v4f* acc) {
  const int node = tb + col;
  const int cl = (node * 205) >> 12;                 // node/20 for node<80
  const v8s b0 = *(const v8s*)(A + node * ASTR + quad * 8);
  const v8s b1 = *(const v8s*)(A + (cl * 4 + quad) * ASTR + 64);  // pad cols
#pragma unroll
  for (int t = 0; t < NT; ++t) {
    v4f a = bias4[t];
    a = MFMA(Wf[t * 2 + 0], b0, a, 0, 0, 0);
    a = MFMA(Wf[t * 2 + 1], b1, a, 0, 0, 0);
    acc[t] = a;
  }
}

// LayerNorm(64)+ReLU, features in-lane; short4 (b64) writes.
__device__ __forceinline__ void lnT_write(short* Aw, int tb, int col, int quad,
                                          v4f* acc, const v4f* g4,
                                          const v4f* be4) {
  float mu = 0.f, sq = 0.f;
#pragma unroll
  for (int t = 0; t < 4; ++t)
#pragma unroll
    for (int r = 0; r < 4; ++r) {
      mu += acc[t][r];
      sq = fmaf(acc[t][r], acc[t][r], sq);
    }
  mu += __shfl_xor(mu, 16); mu += __shfl_xor(mu, 32);
  sq += __shfl_xor(sq, 16); sq += __shfl_xor(sq, 32);
  mu *= (1.0f / 64.0f);
  const float var = sq * (1.0f / 64.0f) - mu * mu;
  const float rs = rsqrtf(var + 1e-5f);
#pragma unroll
  for (int t = 0; t < 4; ++t) {
    short4 s;
#pragma unroll
    for (int r = 0; r < 4; ++r) {
      float v = fmaf((acc[t][r] - mu) * rs, g4[t][r], be4[t][r]);
      ((short*)&s)[r] = bfb(fmaxf(v, 0.f));
    }
    *(short4*)(Aw + (tb + col) * ASTR + t * 16 + quad * 4) = s;
  }
}

template <int NT>
__device__ __forceinline__ void plainT_write(short* Aw, int tb, int col,
                                             int quad, v4f* acc) {
#pragma unroll
  for (int t = 0; t < NT; ++t) {
    short4 s;
#pragma unroll
    for (int r = 0; r < 4; ++r) ((short*)&s)[r] = bfb(acc[t][r]);
    *(short4*)(Aw + (tb + col) * ASTR + t * 16 + quad * 4) = s;
  }
}

// ---- kF: the whole network, one wave = 4 clusters, zero barriers ----
__global__ void __launch_bounds__(128, 2)
kF(const float* __restrict__ x, const int* __restrict__ batch,
   const short* __restrict__ wsW,
   const float* __restrict__ pb1, const float* __restrict__ pg,
   const float* __restrict__ pbe,
   const float* __restrict__ b1a, const float* __restrict__ ga,
   const float* __restrict__ bea, const float* __restrict__ b2a,
   const float* __restrict__ b1b, const float* __restrict__ gb,
   const float* __restrict__ beb, const float* __restrict__ b2b,
   const float* __restrict__ b1c, const float* __restrict__ gc_,
   const float* __restrict__ bec, const float* __restrict__ b2c,
   const float* __restrict__ ob1, const float* __restrict__ og,
   const float* __restrict__ obe, const float* __restrict__ ob2,
   float* __restrict__ out, int C) {
  __shared__ __align__(16) short act[2 * 80 * ASTR];   // 23040 B
  const int tid = threadIdx.x;
  const int lane = tid & 63;
  const int wave = tid >> 6;
  const int col = lane & 15;
  const int quad = lane >> 4;
  const int cbase = blockIdx.x * 8 + wave * 4;
  if (cbase >= C) return;
  const int nc = min(4, C - cbase);
  const int nrows = nc * 20;
  const int ntiles = (nrows + 15) >> 4;
  short* A = act + wave * 80 * ASTR;

  // ---- load x -> bf16 cols 0..15, zero cols 16..31 (as R9) ----
  {
    const float4* x4 = (const float4*)x;
    const long nb = (long)cbase * 20;
    const short4 z = {0, 0, 0, 0};
    for (int i = lane; i < nrows * 4; i += 64) {
      const int row = i >> 2, e = i & 3;
      float4 v = x4[(nb + row) * 4 + e];
      short4 s = {bfb(v.x), bfb(v.y), bfb(v.z), bfb(v.w)};
      *(short4*)(A + row * ASTR + e * 4) = s;
      *(short4*)(A + row * ASTR + 16 + e * 4) = z;
    }
    if (nrows < ntiles * 16) {
      for (int i = lane; i < (ntiles * 16 - nrows) * 18; i += 64) {
        const int row = nrows + i / 18, e = i % 18;
        *(short4*)(A + row * ASTR + e * 4) = z;
      }
    }
  }

  // ---- pre-MLP stage 1: 16(pad32) -> 64, LN, ReLU (as R9) ----
  {
    v8s Wf[4]; v4f b4[4], g4[4], be4[4];
#pragma unroll
    for (int t = 0; t < 4; ++t) {
      Wf[t] = *(const v8s*)(wsW + OFF_PW1 + (t * 16 + col) * 32 + quad * 8);
      b4[t]  = *(const v4f*)(pb1 + t * 16 + quad * 4);
      g4[t]  = *(const v4f*)(pg  + t * 16 + quad * 4);
      be4[t] = *(const v4f*)(pbe + t * 16 + quad * 4);
    }
    for (int T = 0; T < ntiles; ++T) {
      v4f acc[4];
      mmT<4, 1>(A, T * 16, Wf, b4, col, quad, acc);
      lnT_write(A, T * 16, col, quad, acc, g4, be4);
    }
  }

  // (pre-MLP stage 2 fused into layer 0's W1 -- see kT blocks 1/2)

  // ---- 3 subgraph layers (R9's array-of-pointers form) ----
  const float* fb = (const float*)(wsW + OFF_FB);   // fused bias for L0-W1
  const float* B1p[3] = {fb, b1b, b1c};
  const float* Gp[3]  = {ga, gb, gc_};
  const float* BEp[3] = {bea, beb, bec};
  const float* B2p[3] = {b2a, b2b, b2c};

  for (int L = 0; L < 3; ++L) {
    v8s W1f[8], W2f[4];
    v4f b14[4], g4[4], be4[4], b24[2];
    const short* w1 = wsW + OFF_LW1(L);
    const short* w2 = wsW + OFF_LW2(L);
#pragma unroll
    for (int t = 0; t < 4; ++t) {
#pragma unroll
      for (int ks = 0; ks < 2; ++ks)
        W1f[t * 2 + ks] = *(const v8s*)(w1 + (t * 16 + col) * 64 + ks * 32 + quad * 8);
      b14[t] = *(const v4f*)(B1p[L] + t * 16 + quad * 4);
      g4[t]  = *(const v4f*)(Gp[L]  + t * 16 + quad * 4);
      be4[t] = *(const v4f*)(BEp[L] + t * 16 + quad * 4);
    }
#pragma unroll
    for (int t = 0; t < 2; ++t) {
#pragma unroll
      for (int ks = 0; ks < 2; ++ks)
        W2f[t * 2 + ks] = *(const v8s*)(w2 + (t * 16 + col) * 64 + ks * 32 + quad * 8);
      b24[t] = *(const v4f*)(B2p[L] + t * 16 + quad * 4);
    }
    for (int T = 0; T < ntiles; ++T) {
      v4f acc[4];
      if (L == 0)
        mmT<4, 2>(A, T * 16, W1f, b14, col, quad, acc);
      else
        mmT_split<4>(A, T * 16, W1f, b14, col, quad, acc);
      lnT_write(A, T * 16, col, quad, acc, g4, be4);
      v4f h[2];
      mmT<2, 2>(A, T * 16, W2f, b24, col, quad, h);
      plainT_write<2>(A, T * 16, col, quad, h);
    }
    // ---- intra-wave pooling: 4 clusters x 16 uint-cols ----
    {
      const int cl = quad, jp = col;
      if (cl < nc) {
        const uint* AU = (const uint*)A;
        float m0 = -3.4e38f, m1 = -3.4e38f;
#pragma unroll
        for (int r = 0; r < 20; ++r) {
          const uint v = AU[(cl * 20 + r) * (ASTR / 2) + jp];
          m0 = fmaxf(m0, __builtin_bit_cast(float, v << 16));
          m1 = fmaxf(m1, __builtin_bit_cast(float, v & 0xFFFF0000u));
        }
        const uint pv = (uint)(unsigned short)bfb(m0) |
                        ((uint)(unsigned short)bfb(m1) << 16);
        uint* AW = (uint*)A;
        if (L < 2) {
          // compact: row cl*4+u's pad uints 32..35 hold pooled uints 4u..4u+3
          AW[(cl * 4 + (jp >> 2)) * (ASTR / 2) + 32 + (jp & 3)] = pv;
        } else {
          // segmax(concat[h,pooled]) == [pooled,pooled] -> rows 0..3 = pooled
          AW[cl * (ASTR / 2) + jp] = pv;
          AW[cl * (ASTR / 2) + 16 + jp] = pv;
        }
      }
    }
  }

  // ---- fused output MLP on rows 0..15 (rows 0..nc-1 valid) ----
  {
    v8s Wf[8]; v4f b4[4], g4[4], be4[4];
#pragma unroll
    for (int t = 0; t < 4; ++t) {
#pragma unroll
      for (int ks = 0; ks < 2; ++ks)
        Wf[t * 2 + ks] = *(const v8s*)(wsW + OFF_OW1 + (t * 16 + col) * 64 + ks * 32 + quad * 8);
      b4[t]  = *(const v4f*)(ob1 + t * 16 + quad * 4);
      g4[t]  = *(const v4f*)(og  + t * 16 + quad * 4);
      be4[t] = *(const v4f*)(obe + t * 16 + quad * 4);
    }
    v4f acc[4];
    mmT<4, 2>(A, 0, Wf, b4, col, quad, acc);
    lnT_write(A, 0, col, quad, acc, g4, be4);
  }
  {
    v4f acc[8];
    const v8s bb0 = *(const v8s*)(A + col * ASTR + quad * 8);
    const v8s bb1 = *(const v8s*)(A + col * ASTR + 32 + quad * 8);
#pragma unroll
    for (int half = 0; half < 2; ++half) {
      v8s Wf[8];
#pragma unroll
      for (int t = 0; t < 4; ++t)
#pragma unroll
        for (int ks = 0; ks < 2; ++ks)
          Wf[t * 2 + ks] = *(const v8s*)(wsW + OFF_OW2 +
                             ((half * 4 + t) * 16 + col) * 64 + ks * 32 + quad * 8);
#pragma unroll
      for (int t = 0; t < 4; ++t) {
        v4f a = *(const v4f*)(ob2 + (half * 4 + t) * 16 + quad * 4);
        a = MFMA(Wf[t * 2], bb0, a, 0, 0, 0);
        a = MFMA(Wf[t * 2 + 1], bb1, a, 0, 0, 0);
        acc[half * 4 + t] = a;
      }
    }
    // L2 norm over 128 feats (32 in-lane + cross-quad)
    float sq = 0.f;
#pragma unroll
    for (int t = 0; t < 8; ++t)
#pragma unroll
      for (int r = 0; r < 4; ++r) sq = fmaf(acc[t][r], acc[t][r], sq);
    sq += __shfl_xor(sq, 16); sq += __shfl_xor(sq, 32);
    const float inv = 1.0f / fmaxf(sqrtf(sq), 1e-12f);
    if (col < nc) {
      const long gcl = cbase + col;
#pragma unroll
      for (int t = 0; t < 8; ++t) {
        float4 v = {acc[t][0] * inv, acc[t][1] * inv,
                    acc[t][2] * inv, acc[t][3] * inv};
        *(float4*)(out + gcl * 128 + t * 16 + quad * 4) = v;
      }
      if (quad == 0) out[(long)C * 128 + gcl] = (float)batch[gcl * 20];
    }
  }
}

extern "C" void kernel_launch(void* const* d_in, const int* in_sizes, int n_in,
                              void* d_out, int out_size, void* d_ws, size_t ws_size,
                              hipStream_t stream) {
  const float* x     = (const float*)d_in[0];
  const int*   batch = (const int*)d_in[2];
  const float* pw1 = (const float*)d_in[3];
  const float* pb1 = (const float*)d_in[4];
  const float* pg  = (const float*)d_in[5];
  const float* pbe = (const float*)d_in[6];
  const float* pw2 = (const float*)d_in[7];
  const float* pb2 = (const float*)d_in[8];
  const float* w1a = (const float*)d_in[9];
  const float* b1a = (const float*)d_in[10];
  const float* ga  = (const float*)d_in[11];
  const float* bea = (const float*)d_in[12];
  const float* w2a = (const float*)d_in[13];
  const float* b2a = (const float*)d_in[14];
  const float* w1b = (const float*)d_in[15];
  const float* b1b = (const float*)d_in[16];
  const float* gb  = (const float*)d_in[17];
  const float* beb = (const float*)d_in[18];
  const float* w2b = (const float*)d_in[19];
  const float* b2b = (const float*)d_in[20];
  const float* w1c = (const float*)d_in[21];
  const float* b1c = (const float*)d_in[22];
  const float* gc  = (const float*)d_in[23];
  const float* bec = (const float*)d_in[24];
  const float* w2c = (const float*)d_in[25];
  const float* b2c = (const float*)d_in[26];
  const float* ow1 = (const float*)d_in[27];
  const float* ob1 = (const float*)d_in[28];
  const float* og  = (const float*)d_in[29];
  const float* obe = (const float*)d_in[30];
  const float* ow2 = (const float*)d_in[31];
  const float* ob2 = (const float*)d_in[32];

  const int N = in_sizes[0] / 16;
  const int C = N / 20;
  short* ws16 = (short*)d_ws;
  float* out = (float*)d_out;

  hipLaunchKernelGGL(kT, dim3(10), dim3(256), 0, stream,
                     pw1, pw2, w1a, w2a, w1b, w2b, w1c, w2c, ow1, ow2,
                     pb2, b1a, ws16);

  const int blocks = (C + 7) / 8;   // 8 clusters per block (2 waves x 4)
  hipLaunchKernelGGL(kF, dim3(blocks), dim3(128), 0, stream,
                     x, batch, (const short*)ws16,
                     pb1, pg, pbe,
                     b1a, ga, bea, b2a,
                     b1b, gb, beb, b2b,
                     b1c, gc, bec, b2c,
                     ob1, og, obe, ob2,
                     out, C);
}